// Round 7
// baseline (89.854 us; speedup 1.0000x reference)
//
#include <hip/hip_runtime.h>
#include <stdint.h>

typedef _Float16 f16;
typedef f16   f16x2 __attribute__((ext_vector_type(2)));
typedef f16   f16x8 __attribute__((ext_vector_type(8)));
typedef float f32x4 __attribute__((ext_vector_type(4)));

static constexpr int M_ = 64;
static constexpr int K_ = 4096;
static constexpr int N_ = 14336;

// x fp32 [64][4096] -> f16, tiled into MFMA-fragment order:
// f16x8-slot ((kg*4+mt)*64 + h*16 + l16) holds x[mt*16+l16][(kg*4+h)*8 .. +8)
// (kg = global k-step of 32). A chunk of 8 k-steps is a contiguous 32 KB blob.
__global__ void xconv_kernel(const float* __restrict__ x, uint4* __restrict__ xt) {
    int t = blockIdx.x * blockDim.x + threadIdx.x;      // 32768 threads
    int row = t >> 9, kb = t & 511;
    int kg = kb >> 2, h = kb & 3, mt = row >> 4, l16 = row & 15;
    int dst = (kg * 4 + mt) * 64 + h * 16 + l16;
    const float4* p = reinterpret_cast<const float4*>(x) + 2 * (size_t)t;   // coalesced read
    float4 a = p[0], b = p[1];
    union { f16x8 h8; uint4 v; } z;
    z.h8[0] = (f16)a.x; z.h8[1] = (f16)a.y; z.h8[2] = (f16)a.z; z.h8[3] = (f16)a.w;
    z.h8[4] = (f16)b.x; z.h8[5] = (f16)b.y; z.h8[6] = (f16)b.z; z.h8[7] = (f16)b.w;
    xt[dst] = z.v;
}

// nibble->f16 dequant: 0x6400|n = 1024+n exact; pk_add(-1032) -> n-8 exact; pk_mul(s).
// packed dword nibble p -> frag slot 2p, nibble p+4 -> slot 2p+1 (folds pack-perm).
__device__ __forceinline__ f16x8 dequant(uint u, f16x2 sc) {
    const f16 m = (f16)(-1032.0f);
    const f16x2 mc = {m, m};
    union { f16x2 h2; uint uu; } um;
    union { f16x2 h2[4]; f16x8 v; } ob;
    #pragma unroll
    for (int p = 0; p < 4; ++p) {
        um.uu = 0x64006400u | ((u >> (4 * p)) & 0x000F000Fu);
        ob.h2[p] = (um.h2 + mc) * sc;
    }
    return ob.v;
}

// grid=448 (BN=32), block=512=8 waves, 16 K-chunks of 256 (8 k-steps each).
// Wave w owns k-step w of every chunk (4mt x 2nt x 1 kstep => 8 MFMA/chunk).
// A: global->reg (chunk c+2) -> ds_write (chunk c+1) -> ds_read (chunk c),
//    double-buffered LDS 2x32KB. NO global_load_lds anywhere => no vmcnt/LDS
//    legalizer interaction; global prefetches stay in flight across barriers.
// B + scales: pure register prefetch, 2 chunks deep (3-slot rotation).
// Sync: one lgkmcnt(0) + raw s_barrier per chunk. Epilogue: LDS tree-reduce.
template<bool PRE>
__global__ __launch_bounds__(512, 4)
void gemm_kernel(const float* __restrict__ xf, const uint4* __restrict__ xt4,
                 const uint* __restrict__ bpk, const float* __restrict__ s,
                 float* __restrict__ out)
{
    __shared__ __align__(16) uint lbs[16384];           // 64 KB = 2 x 32 KB A-buffers
    const int tid  = threadIdx.x;
    const int lane = tid & 63;
    const int w    = tid >> 6;                          // k-step owner 0..7
    const int h    = lane >> 4;
    const int l16  = lane & 15;
    const int n0   = blockIdx.x * 32;

    auto loadA = [&](int c, uint4 r[4]) {               // chunk c -> 4x16B regs
        #pragma unroll
        for (int q = 0; q < 4; ++q) {
            if constexpr (PRE) {
                r[q] = xt4[(size_t)c * 2048 + q * 512 + tid];
            } else {
                int slot = q * 512 + tid;
                int kg = slot >> 8, rem = slot & 255;
                int mt = rem >> 6, sub = rem & 63, hh = sub >> 4, ll = sub & 15;
                const float* xp = xf + (size_t)(mt * 16 + ll) * K_ + (size_t)((c * 8 + kg) * 4 + hh) * 8;
                float4 f0 = *reinterpret_cast<const float4*>(xp);
                float4 f1 = *reinterpret_cast<const float4*>(xp + 4);
                union { f16x8 h8; uint4 v; } ua;
                ua.h8[0] = (f16)f0.x; ua.h8[1] = (f16)f0.y; ua.h8[2] = (f16)f0.z; ua.h8[3] = (f16)f0.w;
                ua.h8[4] = (f16)f1.x; ua.h8[5] = (f16)f1.y; ua.h8[6] = (f16)f1.z; ua.h8[7] = (f16)f1.w;
                r[q] = ua.v;
            }
        }
    };
    auto writeA = [&](int buf, const uint4 r[4]) {      // contiguous 16B/lane: no conflicts
        uint4* dst = reinterpret_cast<uint4*>(lbs + buf * 8192);
        #pragma unroll
        for (int q = 0; q < 4; ++q) dst[q * 512 + tid] = r[q];
    };
    auto loadB = [&](int c, uint bo[2]) {               // 2 packed dwords (this wave's kstep)
        bo[0] = bpk[(size_t)(n0 +      l16) * 512 + c * 32 + w * 4 + h];
        bo[1] = bpk[(size_t)(n0 + 16 + l16) * 512 + c * 32 + w * 4 + h];
    };
    auto loadS = [&](int c, float so[2]) {              // group = 2c + (w>>2)
        const size_t g = (size_t)(2 * c + (w >> 2)) * N_;
        so[0] = s[g + n0 + l16];
        so[1] = s[g + n0 + 16 + l16];
    };

    uint4 ar[2][4];                                     // A reg double-buffer
    uint  br[3][2];                                     // B 3-slot rotation
    float sf[3][2];
    loadA(0, ar[0]); loadA(1, ar[1]);
    loadB(0, br[0]); loadB(1, br[1]);
    loadS(0, sf[0]); loadS(1, sf[1]);

    writeA(0, ar[0]);                                   // stage chunk 0
    asm volatile("s_waitcnt lgkmcnt(0)" ::: "memory");
    __builtin_amdgcn_s_barrier();
    __builtin_amdgcn_sched_barrier(0);

    f32x4 acc[2][4];
    #pragma unroll
    for (int nt = 0; nt < 2; ++nt)
        #pragma unroll
        for (int mt = 0; mt < 4; ++mt) acc[nt][mt] = f32x4{0.f, 0.f, 0.f, 0.f};

    #pragma unroll
    for (int c = 0; c < 16; ++c) {
        if (c < 14) {                                   // prefetch chunk c+2 (regs only)
            loadA(c + 2, ar[c & 1]);
            loadB(c + 2, br[(c + 2) % 3]);
            loadS(c + 2, sf[(c + 2) % 3]);
        }
        if (c < 15) writeA((c + 1) & 1, ar[(c + 1) & 1]);   // stage chunk c+1

        // ---- compute chunk c from buf[c&1] ----
        const f16x8* bufp = reinterpret_cast<const f16x8*>(lbs + (c & 1) * 8192);
        f16x8 afr[4];
        #pragma unroll
        for (int mt = 0; mt < 4; ++mt)
            afr[mt] = bufp[(w * 4 + mt) * 64 + h * 16 + l16];   // 1KB/wave contig

        const f16 s0 = (f16)sf[c % 3][0], s1 = (f16)sf[c % 3][1];
        const f16x8 b0 = dequant(br[c % 3][0], f16x2{s0, s0});
        const f16x8 b1 = dequant(br[c % 3][1], f16x2{s1, s1});
        #pragma unroll
        for (int mt = 0; mt < 4; ++mt)
            acc[0][mt] = __builtin_amdgcn_mfma_f32_16x16x32_f16(afr[mt], b0, acc[0][mt], 0, 0, 0);
        #pragma unroll
        for (int mt = 0; mt < 4; ++mt)
            acc[1][mt] = __builtin_amdgcn_mfma_f32_16x16x32_f16(afr[mt], b1, acc[1][mt], 0, 0, 0);

        // my writes + my reads done -> signal; vmem prefetches stay in flight
        asm volatile("s_waitcnt lgkmcnt(0)" ::: "memory");
        __builtin_amdgcn_s_barrier();
        __builtin_amdgcn_sched_barrier(0);
    }

    // ---- tree-reduce 8 k-step partials via LDS (alias A buffers) ----
    f32x4* red = reinterpret_cast<f32x4*>(lbs);
    __syncthreads();
    if (w >= 4) {
        #pragma unroll
        for (int nt = 0; nt < 2; ++nt)
            #pragma unroll
            for (int mt = 0; mt < 4; ++mt)
                red[((w - 4) * 8 + nt * 4 + mt) * 64 + lane] = acc[nt][mt];
    }
    __syncthreads();
    if (w < 4) {
        #pragma unroll
        for (int nt = 0; nt < 2; ++nt)
            #pragma unroll
            for (int mt = 0; mt < 4; ++mt)
                acc[nt][mt] += red[(w * 8 + nt * 4 + mt) * 64 + lane];
    }
    __syncthreads();
    if (w == 2 || w == 3) {
        #pragma unroll
        for (int nt = 0; nt < 2; ++nt)
            #pragma unroll
            for (int mt = 0; mt < 4; ++mt)
                red[((w - 2) * 8 + nt * 4 + mt) * 64 + lane] = acc[nt][mt];
    }
    __syncthreads();
    if (w < 2) {
        #pragma unroll
        for (int nt = 0; nt < 2; ++nt)
            #pragma unroll
            for (int mt = 0; mt < 4; ++mt)
                acc[nt][mt] += red[(w * 8 + nt * 4 + mt) * 64 + lane];
    }
    __syncthreads();
    if (w < 2) {
        #pragma unroll
        for (int nt = 0; nt < 2; ++nt)
            #pragma unroll
            for (int mt = 0; mt < 4; ++mt)
                red[(w * 8 + nt * 4 + mt) * 64 + lane] = acc[nt][mt];
    }
    __syncthreads();
    {   // every wave stores one (nt,mt) slot: final = w0-half + w1-half
        const int slot = w;
        f32x4 v = red[slot * 64 + lane];
        v += red[(8 + slot) * 64 + lane];
        const int nt = slot >> 2, mt = slot & 3;
        #pragma unroll
        for (int q = 0; q < 4; ++q)
            out[(size_t)(mt * 16 + h * 4 + q) * N_ + (n0 + nt * 16 + l16)] = v[q];
    }
}

extern "C" void kernel_launch(void* const* d_in, const int* in_sizes, int n_in,
                              void* d_out, int out_size, void* d_ws, size_t ws_size,
                              hipStream_t stream) {
    const float* x   = (const float*)d_in[0];
    const uint*  bpk = (const uint*)d_in[1];
    const float* s   = (const float*)d_in[2];
    float*       out = (float*)d_out;

    if (ws_size >= (size_t)(M_ * K_ * 2)) {
        xconv_kernel<<<128, 256, 0, stream>>>(x, (uint4*)d_ws);
        gemm_kernel<true><<<448, 512, 0, stream>>>(x, (const uint4*)d_ws, bpk, s, out);
    } else {
        gemm_kernel<false><<<448, 512, 0, stream>>>(x, nullptr, bpk, s, out);
    }
}

// Round 8
// 36.348 us; speedup vs baseline: 2.4721x; 2.4721x over previous
//
#include <hip/hip_runtime.h>
#include <stdint.h>

typedef _Float16 f16;
typedef f16   f16x2 __attribute__((ext_vector_type(2)));
typedef f16   f16x8 __attribute__((ext_vector_type(8)));
typedef float f32x4 __attribute__((ext_vector_type(4)));

static constexpr int M_ = 64;
static constexpr int K_ = 4096;
static constexpr int N_ = 14336;

// x fp32 [64][4096] -> f16, tiled into MFMA-fragment order:
// f16x8-slot ((kg*4+mt)*64 + h*16 + l16) holds x[mt*16+l16][(kg*4+h)*8 .. +8)
// (kg = global k-step of 32). A chunk of 8 k-steps = contiguous 32 KB blob.
__global__ void xconv_kernel(const float* __restrict__ x, uint4* __restrict__ xt) {
    int t = blockIdx.x * blockDim.x + threadIdx.x;      // 32768 threads
    int row = t >> 9, kb = t & 511;
    int kg = kb >> 2, h = kb & 3, mt = row >> 4, l16 = row & 15;
    int dst = (kg * 4 + mt) * 64 + h * 16 + l16;
    const float4* p = reinterpret_cast<const float4*>(x) + 2 * (size_t)t;   // coalesced read
    float4 a = p[0], b = p[1];
    union { f16x8 h8; uint4 v; } z;
    z.h8[0] = (f16)a.x; z.h8[1] = (f16)a.y; z.h8[2] = (f16)a.z; z.h8[3] = (f16)a.w;
    z.h8[4] = (f16)b.x; z.h8[5] = (f16)b.y; z.h8[6] = (f16)b.z; z.h8[7] = (f16)b.w;
    xt[dst] = z.v;
}

// nibble->f16 dequant: 0x6400|n = 1024+n exact; pk_add(-1032) -> n-8 exact; pk_mul(s).
// packed dword nibble p -> frag slot 2p, nibble p+4 -> slot 2p+1 (folds pack-perm).
__device__ __forceinline__ f16x8 dequant(uint u, f16x2 sc) {
    const f16 m = (f16)(-1032.0f);
    const f16x2 mc = {m, m};
    union { f16x2 h2; uint uu; } um;
    union { f16x2 h2[4]; f16x8 v; } ob;
    #pragma unroll
    for (int p = 0; p < 4; ++p) {
        um.uu = 0x64006400u | ((u >> (4 * p)) & 0x000F000Fu);
        ob.h2[p] = (um.h2 + mc) * sc;
    }
    return ob.v;
}

struct A4 { uint4 q0, q1, q2, q3; };    // one chunk's A slice per thread (64 B)
struct U2 { uint  a, b; };
struct F2 { float a, b; };

// grid=448 (BN=32), block=512=8 waves, 16 K-chunks of 256 (8 k-steps each).
// Wave w owns k-step w of every chunk (4mt x 2nt => 8 MFMA/chunk).
// A: global->NAMED regs (chunk c+2) -> ds_write (chunk c+1) -> ds_read (chunk c),
//    LDS 2x32KB double-buffer. No global_load_lds; vmem prefetches stay in
//    flight across raw s_barriers; only lgkmcnt(0) drains per chunk.
// ALL pipelined state is named scalars/structs (rule #20: no local arrays).
template<bool PRE>
__global__ __launch_bounds__(512, 4)
void gemm_kernel(const float* __restrict__ xf, const uint4* __restrict__ xt4,
                 const uint* __restrict__ bpk, const float* __restrict__ s,
                 float* __restrict__ out)
{
    __shared__ __align__(16) uint lbs[16384];           // 64 KB = 2 x 32 KB A-buffers
    const int tid  = threadIdx.x;
    const int lane = tid & 63;
    const int w    = tid >> 6;                          // k-step owner 0..7
    const int h    = lane >> 4;
    const int l16  = lane & 15;
    const int n0   = blockIdx.x * 32;

    auto loadA = [&](int c) -> A4 {
        A4 r;
        if constexpr (PRE) {
            const uint4* p = xt4 + (size_t)c * 2048 + tid;
            r.q0 = p[0]; r.q1 = p[512]; r.q2 = p[1024]; r.q3 = p[1536];
        } else {
            uint4* rq[4] = {&r.q0, &r.q1, &r.q2, &r.q3};
            #pragma unroll
            for (int q = 0; q < 4; ++q) {
                int slot = q * 512 + tid;
                int kg = slot >> 8, rem = slot & 255;
                int mt = rem >> 6, sub = rem & 63, hh = sub >> 4, ll = sub & 15;
                const float* xp = xf + (size_t)(mt * 16 + ll) * K_ + (size_t)((c * 8 + kg) * 4 + hh) * 8;
                float4 f0 = *reinterpret_cast<const float4*>(xp);
                float4 f1 = *reinterpret_cast<const float4*>(xp + 4);
                union { f16x8 h8; uint4 v; } ua;
                ua.h8[0] = (f16)f0.x; ua.h8[1] = (f16)f0.y; ua.h8[2] = (f16)f0.z; ua.h8[3] = (f16)f0.w;
                ua.h8[4] = (f16)f1.x; ua.h8[5] = (f16)f1.y; ua.h8[6] = (f16)f1.z; ua.h8[7] = (f16)f1.w;
                *rq[q] = ua.v;
            }
        }
        return r;
    };
    auto writeA = [&](int buf, A4 r) {                  // 64 contig uint4/wave: conflict-free
        uint4* dst = reinterpret_cast<uint4*>(lbs) + buf * 2048 + tid;
        dst[0] = r.q0; dst[512] = r.q1; dst[1024] = r.q2; dst[1536] = r.q3;
    };
    auto loadB = [&](int c) -> U2 {
        U2 r;
        r.a = bpk[(size_t)(n0 +      l16) * 512 + c * 32 + w * 4 + h];
        r.b = bpk[(size_t)(n0 + 16 + l16) * 512 + c * 32 + w * 4 + h];
        return r;
    };
    auto loadS = [&](int c) -> F2 {
        const size_t g = (size_t)(2 * c + (w >> 2)) * N_;
        F2 r; r.a = s[g + n0 + l16]; r.b = s[g + n0 + 16 + l16];
        return r;
    };

    // named accumulators (no arrays anywhere in the hot path)
    f32x4 c00 = {0,0,0,0}, c01 = {0,0,0,0}, c02 = {0,0,0,0}, c03 = {0,0,0,0};
    f32x4 c10 = {0,0,0,0}, c11 = {0,0,0,0}, c12 = {0,0,0,0}, c13 = {0,0,0,0};

    A4 aE = loadA(0), aO = loadA(1);
    U2 bE = loadB(0), bO = loadB(1);
    F2 sE = loadS(0), sO = loadS(1);

    writeA(0, aE);                                      // stage chunk 0 -> buf0
    asm volatile("s_waitcnt lgkmcnt(0)" ::: "memory");
    __builtin_amdgcn_s_barrier();
    __builtin_amdgcn_sched_barrier(0);

#define COMPUTE(BUF, UB, US)                                                     \
    {                                                                            \
        const f16x8* bufp = reinterpret_cast<const f16x8*>(lbs + (BUF) * 8192);  \
        const f16x8 af0 = bufp[(w * 4 + 0) * 64 + lane];                         \
        const f16x8 af1 = bufp[(w * 4 + 1) * 64 + lane];                         \
        const f16x8 af2 = bufp[(w * 4 + 2) * 64 + lane];                         \
        const f16x8 af3 = bufp[(w * 4 + 3) * 64 + lane];                         \
        const f16 sh0 = (f16)(US).a, sh1 = (f16)(US).b;                          \
        const f16x8 bq0 = dequant((UB).a, f16x2{sh0, sh0});                      \
        const f16x8 bq1 = dequant((UB).b, f16x2{sh1, sh1});                      \
        c00 = __builtin_amdgcn_mfma_f32_16x16x32_f16(af0, bq0, c00, 0, 0, 0);    \
        c01 = __builtin_amdgcn_mfma_f32_16x16x32_f16(af1, bq0, c01, 0, 0, 0);    \
        c02 = __builtin_amdgcn_mfma_f32_16x16x32_f16(af2, bq0, c02, 0, 0, 0);    \
        c03 = __builtin_amdgcn_mfma_f32_16x16x32_f16(af3, bq0, c03, 0, 0, 0);    \
        c10 = __builtin_amdgcn_mfma_f32_16x16x32_f16(af0, bq1, c10, 0, 0, 0);    \
        c11 = __builtin_amdgcn_mfma_f32_16x16x32_f16(af1, bq1, c11, 0, 0, 0);    \
        c12 = __builtin_amdgcn_mfma_f32_16x16x32_f16(af2, bq1, c12, 0, 0, 0);    \
        c13 = __builtin_amdgcn_mfma_f32_16x16x32_f16(af3, bq1, c13, 0, 0, 0);    \
    }

    #pragma unroll
    for (int cc = 0; cc < 8; ++cc) {
        const int c0 = 2 * cc, c1 = 2 * cc + 1;
        {   // even chunk c0: compute buf0; stage c0+1 -> buf1; prefetch c0+2
            const U2 ub = bE; const F2 us = sE;
            if (c0 + 2 < 16) { aE = loadA(c0 + 2); bE = loadB(c0 + 2); sE = loadS(c0 + 2); }
            writeA(1, aO);
            COMPUTE(0, ub, us)
            asm volatile("s_waitcnt lgkmcnt(0)" ::: "memory");
            __builtin_amdgcn_s_barrier();
            __builtin_amdgcn_sched_barrier(0);
        }
        {   // odd chunk c1: compute buf1; stage c1+1 -> buf0; prefetch c1+2
            const U2 ub = bO; const F2 us = sO;
            if (c1 + 2 < 16) { aO = loadA(c1 + 2); bO = loadB(c1 + 2); sO = loadS(c1 + 2); }
            if (c1 + 1 < 16) writeA(0, aE);
            COMPUTE(1, ub, us)
            asm volatile("s_waitcnt lgkmcnt(0)" ::: "memory");
            __builtin_amdgcn_s_barrier();
            __builtin_amdgcn_sched_barrier(0);
        }
    }
#undef COMPUTE

    // ---- flat LDS exchange of the 8 k-step partials (alias A buffers, 64 KB) ----
    f32x4* red = reinterpret_cast<f32x4*>(lbs);
#define STORE_ACC(SLOT, V) red[(w * 8 + (SLOT)) * 64 + lane] = V;
    STORE_ACC(0, c00) STORE_ACC(1, c01) STORE_ACC(2, c02) STORE_ACC(3, c03)
    STORE_ACC(4, c10) STORE_ACC(5, c11) STORE_ACC(6, c12) STORE_ACC(7, c13)
#undef STORE_ACC
    __syncthreads();
    {   // wave w owns output slot w: nt = w>>2, mt = w&3; sum over 8 k-partials
        f32x4 v = red[(0 * 8 + w) * 64 + lane];
        v += red[(1 * 8 + w) * 64 + lane];
        v += red[(2 * 8 + w) * 64 + lane];
        v += red[(3 * 8 + w) * 64 + lane];
        v += red[(4 * 8 + w) * 64 + lane];
        v += red[(5 * 8 + w) * 64 + lane];
        v += red[(6 * 8 + w) * 64 + lane];
        v += red[(7 * 8 + w) * 64 + lane];
        const int nt = w >> 2, mt = w & 3;
        #pragma unroll
        for (int q = 0; q < 4; ++q)
            out[(size_t)(mt * 16 + h * 4 + q) * N_ + (n0 + nt * 16 + l16)] = v[q];
    }
}

extern "C" void kernel_launch(void* const* d_in, const int* in_sizes, int n_in,
                              void* d_out, int out_size, void* d_ws, size_t ws_size,
                              hipStream_t stream) {
    const float* x   = (const float*)d_in[0];
    const uint*  bpk = (const uint*)d_in[1];
    const float* s   = (const float*)d_in[2];
    float*       out = (float*)d_out;

    if (ws_size >= (size_t)(M_ * K_ * 2)) {
        xconv_kernel<<<128, 256, 0, stream>>>(x, (uint4*)d_ws);
        gemm_kernel<true><<<448, 512, 0, stream>>>(x, (const uint4*)d_ws, bpk, s, out);
    } else {
        gemm_kernel<false><<<448, 512, 0, stream>>>(x, nullptr, bpk, s, out);
    }
}

// Round 9
// 33.697 us; speedup vs baseline: 2.6665x; 1.0787x over previous
//
#include <hip/hip_runtime.h>
#include <stdint.h>

typedef _Float16 f16;
typedef f16   f16x2 __attribute__((ext_vector_type(2)));
typedef f16   f16x8 __attribute__((ext_vector_type(8)));
typedef float f32x4 __attribute__((ext_vector_type(4)));

static constexpr int M_ = 64;
static constexpr int K_ = 4096;
static constexpr int N_ = 14336;

// x fp32 [64][4096] -> f16, tiled into MFMA-fragment order:
// f16x8-slot ((kg*4+mt)*64 + h*16 + l16) holds x[mt*16+l16][(kg*4+h)*8 .. +8)
// (kg = global k-step of 32) => a wave's A-fragment load is base + lane*16B.
__global__ void xconv_kernel(const float* __restrict__ x, uint4* __restrict__ xt) {
    int t = blockIdx.x * blockDim.x + threadIdx.x;      // 32768 threads
    int row = t >> 9, kb = t & 511;
    int kg = kb >> 2, h = kb & 3, mt = row >> 4, l16 = row & 15;
    int dst = (kg * 4 + mt) * 64 + h * 16 + l16;
    const float4* p = reinterpret_cast<const float4*>(x) + 2 * (size_t)t;   // coalesced read
    float4 a = p[0], b = p[1];
    union { f16x8 h8; uint4 v; } z;
    z.h8[0] = (f16)a.x; z.h8[1] = (f16)a.y; z.h8[2] = (f16)a.z; z.h8[3] = (f16)a.w;
    z.h8[4] = (f16)b.x; z.h8[5] = (f16)b.y; z.h8[6] = (f16)b.z; z.h8[7] = (f16)b.w;
    xt[dst] = z.v;
}

// nibble->f16 dequant: 0x6400|n = 1024+n exact; pk_add(-1032) -> n-8 exact; pk_mul(s).
// packed dword nibble p -> frag slot 2p, nibble p+4 -> slot 2p+1 (folds pack-perm).
__device__ __forceinline__ f16x8 dequant(uint u, f16x2 sc) {
    const f16 m = (f16)(-1032.0f);
    const f16x2 mc = {m, m};
    union { f16x2 h2; uint uu; } um;
    union { f16x2 h2[4]; f16x8 v; } ob;
    #pragma unroll
    for (int p = 0; p < 4; ++p) {
        um.uu = 0x64006400u | ((u >> (4 * p)) & 0x000F000Fu);
        ob.h2[p] = (um.h2 + mc) * sc;
    }
    return ob.v;
}

// grid=448 (BN=32), block=256 = 4 waves. Wave w owns K-chunk [w*1024,(w+1)*1024)
// = 8 scale-groups = 32 k-steps; computes 4mt x 2nt (acc 32 VGPR).
// NO LDS / NO barriers / NO inline asm in the main loop:
//  - ALL B (64 dwords) + 16 scales preloaded to registers before the loop
//    (issued before any steady-state A-load => in-order vmcnt retirement never
//    makes an A-wait block on HBM-latency B).
//  - A: 4-deep register pipeline from fragment-tiled xt (issue-to-use = 4
//    k-step periods ~ 300-500 cyc, covering L2/L3 latency). All indices
//    compile-time (full unroll) => SROA keeps everything in registers.
// Epilogue: single 32KB LDS exchange, one barrier.
template<bool PRE>
__global__ __launch_bounds__(256, 2)
void gemm_kernel(const float* __restrict__ xf, const f16x8* __restrict__ xt8,
                 const uint* __restrict__ bpk, const float* __restrict__ s,
                 float* __restrict__ out)
{
    __shared__ f32x4 red[4][8][64];                     // 32 KB, epilogue only
    const int tid  = threadIdx.x;
    const int lane = tid & 63;
    const int w    = tid >> 6;                          // K-chunk id 0..3
    const int h    = lane >> 4;
    const int l16  = lane & 15;
    const int n0   = blockIdx.x * 32;

    // ---- ALL B + scales upfront (issued before any A) ----
    // dword for (global kstep kg = w*32+ks, lane h) = kg*4 + h = w*128 + g*16 + t*4 + h
    const uint* br0 = bpk + (size_t)(n0 +      l16) * 512 + w * 128 + h;
    const uint* br1 = bpk + (size_t)(n0 + 16 + l16) * 512 + w * 128 + h;
    uint bv[8][4][2];
    #pragma unroll
    for (int g = 0; g < 8; ++g)
        #pragma unroll
        for (int t = 0; t < 4; ++t) {
            bv[g][t][0] = br0[g * 16 + t * 4];
            bv[g][t][1] = br1[g * 16 + t * 4];
        }
    f16x2 sv[8][2];
    #pragma unroll
    for (int g = 0; g < 8; ++g) {
        float f0 = s[(size_t)(w * 8 + g) * N_ + n0 + l16];
        float f1 = s[(size_t)(w * 8 + g) * N_ + n0 + 16 + l16];
        f16 h0 = (f16)f0, h1 = (f16)f1;
        sv[g][0] = f16x2{h0, h0};
        sv[g][1] = f16x2{h1, h1};
    }

    const f16x8* aw = nullptr;
    if constexpr (PRE) aw = xt8 + (size_t)w * 8192 + lane;   // fragment-tiled base

#define LOAD_A(DST, KS, MT)                                                                    \
    if constexpr (PRE) { DST = aw[((KS) * 4 + (MT)) * 64]; }                                   \
    else {                                                                                     \
        const float* xp_ = xf + (size_t)((MT) * 16 + l16) * K_ + (size_t)(w * 32 + (KS)) * 32 + h * 8; \
        float4 f0_ = *reinterpret_cast<const float4*>(xp_);                                    \
        float4 f1_ = *reinterpret_cast<const float4*>(xp_ + 4);                                \
        f16x8 av_;                                                                             \
        av_[0] = (f16)f0_.x; av_[1] = (f16)f0_.y; av_[2] = (f16)f0_.z; av_[3] = (f16)f0_.w;    \
        av_[4] = (f16)f1_.x; av_[5] = (f16)f1_.y; av_[6] = (f16)f1_.z; av_[7] = (f16)f1_.w;    \
        DST = av_;                                                                             \
    }

    // ---- A pipeline prologue: 4 k-steps deep ----
    f16x8 ap[4][4];
    #pragma unroll
    for (int ks = 0; ks < 4; ++ks)
        #pragma unroll
        for (int mt = 0; mt < 4; ++mt) { LOAD_A(ap[ks][mt], ks, mt) }

    f32x4 acc[2][4];
    #pragma unroll
    for (int nt = 0; nt < 2; ++nt)
        #pragma unroll
        for (int mt = 0; mt < 4; ++mt) acc[nt][mt] = f32x4{0.f, 0.f, 0.f, 0.f};

    // ---- main loop: 32 k-steps, fully unrolled, pure register dataflow ----
    #pragma unroll
    for (int ks = 0; ks < 32; ++ks) {
        const int g = ks >> 2, t = ks & 3;
        const f16x8 a0 = ap[ks & 3][0];
        const f16x8 a1 = ap[ks & 3][1];
        const f16x8 a2 = ap[ks & 3][2];
        const f16x8 a3 = ap[ks & 3][3];
        if (ks + 4 < 32) {                              // refill slot with ks+4
            #pragma unroll
            for (int mt = 0; mt < 4; ++mt) { LOAD_A(ap[ks & 3][mt], ks + 4, mt) }
        }
        const f16x8 b0 = dequant(bv[g][t][0], sv[g][0]);
        const f16x8 b1 = dequant(bv[g][t][1], sv[g][1]);
        acc[0][0] = __builtin_amdgcn_mfma_f32_16x16x32_f16(a0, b0, acc[0][0], 0, 0, 0);
        acc[0][1] = __builtin_amdgcn_mfma_f32_16x16x32_f16(a1, b0, acc[0][1], 0, 0, 0);
        acc[0][2] = __builtin_amdgcn_mfma_f32_16x16x32_f16(a2, b0, acc[0][2], 0, 0, 0);
        acc[0][3] = __builtin_amdgcn_mfma_f32_16x16x32_f16(a3, b0, acc[0][3], 0, 0, 0);
        acc[1][0] = __builtin_amdgcn_mfma_f32_16x16x32_f16(a0, b1, acc[1][0], 0, 0, 0);
        acc[1][1] = __builtin_amdgcn_mfma_f32_16x16x32_f16(a1, b1, acc[1][1], 0, 0, 0);
        acc[1][2] = __builtin_amdgcn_mfma_f32_16x16x32_f16(a2, b1, acc[1][2], 0, 0, 0);
        acc[1][3] = __builtin_amdgcn_mfma_f32_16x16x32_f16(a3, b1, acc[1][3], 0, 0, 0);
    }
#undef LOAD_A

    // ---- epilogue: exchange 4 K-partials via LDS, one barrier ----
    #pragma unroll
    for (int nt = 0; nt < 2; ++nt)
        #pragma unroll
        for (int mt = 0; mt < 4; ++mt)
            red[w][nt * 4 + mt][lane] = acc[nt][mt];
    __syncthreads();
    #pragma unroll
    for (int i = 0; i < 2; ++i) {                       // wave w owns slots 2w, 2w+1
        const int slot = w * 2 + i;
        f32x4 v = red[0][slot][lane];
        v += red[1][slot][lane];
        v += red[2][slot][lane];
        v += red[3][slot][lane];
        const int nt = slot >> 2, mt = slot & 3;        // C/D: row=mt*16+h*4+q, col=n0+nt*16+l16
        #pragma unroll
        for (int q = 0; q < 4; ++q)
            out[(size_t)(mt * 16 + h * 4 + q) * N_ + (n0 + nt * 16 + l16)] = v[q];
    }
}

extern "C" void kernel_launch(void* const* d_in, const int* in_sizes, int n_in,
                              void* d_out, int out_size, void* d_ws, size_t ws_size,
                              hipStream_t stream) {
    const float* x   = (const float*)d_in[0];
    const uint*  bpk = (const uint*)d_in[1];
    const float* s   = (const float*)d_in[2];
    float*       out = (float*)d_out;

    if (ws_size >= (size_t)(M_ * K_ * 2)) {
        xconv_kernel<<<128, 256, 0, stream>>>(x, (uint4*)d_ws);
        gemm_kernel<true><<<448, 256, 0, stream>>>(x, (const f16x8*)d_ws, bpk, s, out);
    } else {
        gemm_kernel<false><<<448, 256, 0, stream>>>(x, nullptr, bpk, s, out);
    }
}

// Round 10
// 24.961 us; speedup vs baseline: 3.5998x; 1.3500x over previous
//
#include <hip/hip_runtime.h>
#include <stdint.h>

typedef _Float16 f16;
typedef f16   f16x2 __attribute__((ext_vector_type(2)));
typedef f16   f16x8 __attribute__((ext_vector_type(8)));
typedef float f32x4 __attribute__((ext_vector_type(4)));

static constexpr int M_ = 64;
static constexpr int K_ = 4096;
static constexpr int N_ = 14336;

// x fp32 [64][4096] -> f16, tiled into MFMA-fragment order:
// f16x8-slot ((kg*4+mt)*64 + h*16 + l16) holds x[mt*16+l16][(kg*4+h)*8 .. +8)
__global__ void xconv_kernel(const float* __restrict__ x, uint4* __restrict__ xt) {
    int t = blockIdx.x * blockDim.x + threadIdx.x;      // 32768 threads
    int row = t >> 9, kb = t & 511;
    int kg = kb >> 2, h = kb & 3, mt = row >> 4, l16 = row & 15;
    int dst = (kg * 4 + mt) * 64 + h * 16 + l16;
    const float4* p = reinterpret_cast<const float4*>(x) + 2 * (size_t)t;   // coalesced read
    float4 a = p[0], b = p[1];
    union { f16x8 h8; uint4 v; } z;
    z.h8[0] = (f16)a.x; z.h8[1] = (f16)a.y; z.h8[2] = (f16)a.z; z.h8[3] = (f16)a.w;
    z.h8[4] = (f16)b.x; z.h8[5] = (f16)b.y; z.h8[6] = (f16)b.z; z.h8[7] = (f16)b.w;
    xt[dst] = z.v;
}

// nibble->f16 dequant: 0x6400|n = 1024+n exact; pk_add(-1032) -> n-8 exact; pk_mul(s).
// packed dword nibble p -> frag slot 2p, nibble p+4 -> slot 2p+1 (folds pack-perm).
__device__ __forceinline__ f16x8 dequant(uint u, f16x2 sc) {
    const f16 m = (f16)(-1032.0f);
    const f16x2 mc = {m, m};
    union { f16x2 h2; uint uu; } um;
    union { f16x2 h2[4]; f16x8 v; } ob;
    #pragma unroll
    for (int p = 0; p < 4; ++p) {
        um.uu = 0x64006400u | ((u >> (4 * p)) & 0x000F000Fu);
        ob.h2[p] = (um.h2 + mc) * sc;
    }
    return ob.v;
}

// grid=448 (BN=32), block=512=8 waves. Wave w owns K-chunk [w*512,(w+1)*512).
// B: global->reg (dwordx4) -> ds_write_b128 -> ds_read b32, all wave-private,
// no barriers / no global_load_lds / no inline asm in the main loop.
// A: fragment-tiled xt, depth-2 k-step register prefetch. acc 4mt x 2nt.
template<bool PRE>
__global__ __launch_bounds__(512, 4)
void gemm_kernel(const float* __restrict__ xf, const f16x8* __restrict__ xt8,
                 const uint* __restrict__ bpk, const float* __restrict__ s,
                 float* __restrict__ out)
{
    __shared__ __align__(16) uint lbs[16384];           // 64 KB (B: 32 KB, epilogue: 64 KB)
    const int tid  = threadIdx.x;
    const int lane = tid & 63;
    const int w    = tid >> 6;                          // K-chunk id 0..7
    const int h    = lane >> 4;
    const int l16  = lane & 15;
    const int n0   = blockIdx.x * 32;

    f16x2 sc0[4], sc1[4];                               // per-group scales (const-indexed)
    #pragma unroll
    for (int g = 0; g < 4; ++g) {
        float a = s[(size_t)(w * 4 + g) * N_ + n0 + l16];
        float b = s[(size_t)(w * 4 + g) * N_ + n0 + 16 + l16];
        f16 ha = (f16)a, hb = (f16)b;
        sc0[g] = f16x2{ha, ha};
        sc1[g] = f16x2{hb, hb};
    }

#define LOADB(G, R0, R1)                                                              \
    {                                                                                 \
        const uint* p0_ = bpk + (size_t)(n0 +      l16) * 512 + w * 64 + (G) * 16 + h * 4; \
        const uint* p1_ = bpk + (size_t)(n0 + 16 + l16) * 512 + w * 64 + (G) * 16 + h * 4; \
        R0 = *reinterpret_cast<const uint4*>(p0_);                                    \
        R1 = *reinterpret_cast<const uint4*>(p1_);                                    \
    }
#define WRITEB(BUF, R0, R1)                                                           \
    {                                                                                 \
        uint4* d_ = reinterpret_cast<uint4*>(lbs + w * 1024 + (BUF) * 512) + lane;    \
        d_[0] = R0; d_[64] = R1;                                                      \
    }
#define LOADA(DST, KS, MT)                                                                         \
    if constexpr (PRE) { DST = xt8[(size_t)(((w * 16 + (KS)) * 4 + (MT)) * 64 + lane)]; }          \
    else {                                                                                         \
        const float* xp_ = xf + (size_t)((MT) * 16 + l16) * K_ + (size_t)(w * 16 + (KS)) * 32 + h * 8; \
        float4 f0_ = *reinterpret_cast<const float4*>(xp_);                                        \
        float4 f1_ = *reinterpret_cast<const float4*>(xp_ + 4);                                    \
        f16x8 av_;                                                                                 \
        av_[0] = (f16)f0_.x; av_[1] = (f16)f0_.y; av_[2] = (f16)f0_.z; av_[3] = (f16)f0_.w;        \
        av_[4] = (f16)f1_.x; av_[5] = (f16)f1_.y; av_[6] = (f16)f1_.z; av_[7] = (f16)f1_.w;        \
        DST = av_;                                                                                 \
    }

    uint4 tE0, tE1, tO0, tO1;                           // named B transit
    LOADB(0, tE0, tE1)
    LOADB(1, tO0, tO1)
    WRITEB(0, tE0, tE1)                                 // stage group 0 (one-time stall)

    f16x8 ap[2][4];                                     // A depth-2 pipeline (const-indexed)
    #pragma unroll
    for (int mt = 0; mt < 4; ++mt) { LOADA(ap[0][mt], 0, mt) }
    #pragma unroll
    for (int mt = 0; mt < 4; ++mt) { LOADA(ap[1][mt], 1, mt) }

    f32x4 acc[2][4];
    #pragma unroll
    for (int nt = 0; nt < 2; ++nt)
        #pragma unroll
        for (int mt = 0; mt < 4; ++mt) acc[nt][mt] = f32x4{0.f, 0.f, 0.f, 0.f};

    // capture A for k-step BEFORE refilling the slot (correct ordering)
#define COMPUTE_T(G, T, U0, U1)                                                           \
    {                                                                                     \
        const f16x8 a0_ = ap[((G) * 4 + (T)) & 1][0];                                     \
        const f16x8 a1_ = ap[((G) * 4 + (T)) & 1][1];                                     \
        const f16x8 a2_ = ap[((G) * 4 + (T)) & 1][2];                                     \
        const f16x8 a3_ = ap[((G) * 4 + (T)) & 1][3];                                     \
        if ((G) * 4 + (T) + 2 < 16) {                                                     \
            LOADA(ap[((G) * 4 + (T)) & 1][0], (G) * 4 + (T) + 2, 0)                       \
            LOADA(ap[((G) * 4 + (T)) & 1][1], (G) * 4 + (T) + 2, 1)                       \
            LOADA(ap[((G) * 4 + (T)) & 1][2], (G) * 4 + (T) + 2, 2)                       \
            LOADA(ap[((G) * 4 + (T)) & 1][3], (G) * 4 + (T) + 2, 3)                       \
        }                                                                                 \
        const f16x8 b0_ = dequant(U0, sc0[(G)]);                                          \
        const f16x8 b1_ = dequant(U1, sc1[(G)]);                                          \
        acc[0][0] = __builtin_amdgcn_mfma_f32_16x16x32_f16(a0_, b0_, acc[0][0], 0, 0, 0); \
        acc[0][1] = __builtin_amdgcn_mfma_f32_16x16x32_f16(a1_, b0_, acc[0][1], 0, 0, 0); \
        acc[0][2] = __builtin_amdgcn_mfma_f32_16x16x32_f16(a2_, b0_, acc[0][2], 0, 0, 0); \
        acc[0][3] = __builtin_amdgcn_mfma_f32_16x16x32_f16(a3_, b0_, acc[0][3], 0, 0, 0); \
        acc[1][0] = __builtin_amdgcn_mfma_f32_16x16x32_f16(a0_, b1_, acc[1][0], 0, 0, 0); \
        acc[1][1] = __builtin_amdgcn_mfma_f32_16x16x32_f16(a1_, b1_, acc[1][1], 0, 0, 0); \
        acc[1][2] = __builtin_amdgcn_mfma_f32_16x16x32_f16(a2_, b1_, acc[1][2], 0, 0, 0); \
        acc[1][3] = __builtin_amdgcn_mfma_f32_16x16x32_f16(a3_, b1_, acc[1][3], 0, 0, 0); \
    }

#define GROUP(G, WBUF, WR0, WR1, DOWRITE)                                             \
    {                                                                                 \
        const int rb_ = w * 1024 + ((G) & 1) * 512 + l16 * 4 + h;                     \
        const uint u00_ = lbs[rb_ +   0], u01_ = lbs[rb_ +  64];                      \
        const uint u02_ = lbs[rb_ + 128], u03_ = lbs[rb_ + 192];                      \
        const uint u10_ = lbs[rb_ + 256], u11_ = lbs[rb_ + 320];                      \
        const uint u12_ = lbs[rb_ + 384], u13_ = lbs[rb_ + 448];                      \
        COMPUTE_T(G, 0, u00_, u10_)                                                   \
        if (DOWRITE) { WRITEB(WBUF, WR0, WR1) }                                       \
        COMPUTE_T(G, 1, u01_, u11_)                                                   \
        COMPUTE_T(G, 2, u02_, u12_)                                                   \
        COMPUTE_T(G, 3, u03_, u13_)                                                   \
    }

    { LOADB(2, tE0, tE1) }                              // issue g2 ~1.5 groups early
    GROUP(0, 1, tO0, tO1, true)                         // compute g0, stage g1
    { LOADB(3, tO0, tO1) }                              // issue g3
    GROUP(1, 0, tE0, tE1, true)                         // compute g1, stage g2
    GROUP(2, 1, tO0, tO1, true)                         // compute g2, stage g3
    GROUP(3, 0, tE0, tE1, false)                        // compute g3 (no more staging)

#undef GROUP
#undef COMPUTE_T
#undef LOADA
#undef WRITEB
#undef LOADB

    // ---- epilogue: flat LDS exchange of the 8 K-partials ----
    __syncthreads();
    f32x4* red = reinterpret_cast<f32x4*>(lbs);
    #pragma unroll
    for (int nt = 0; nt < 2; ++nt)
        #pragma unroll
        for (int mt = 0; mt < 4; ++mt)
            red[(w * 8 + nt * 4 + mt) * 64 + lane] = acc[nt][mt];
    __syncthreads();
    {
        f32x4 v = red[(0 * 8 + w) * 64 + lane];
        v += red[(1 * 8 + w) * 64 + lane];
        v += red[(2 * 8 + w) * 64 + lane];
        v += red[(3 * 8 + w) * 64 + lane];
        v += red[(4 * 8 + w) * 64 + lane];
        v += red[(5 * 8 + w) * 64 + lane];
        v += red[(6 * 8 + w) * 64 + lane];
        v += red[(7 * 8 + w) * 64 + lane];
        const int nt = w >> 2, mt = w & 3;
        #pragma unroll
        for (int q = 0; q < 4; ++q)
            out[(size_t)(mt * 16 + h * 4 + q) * N_ + (n0 + nt * 16 + l16)] = v[q];
    }
}

extern "C" void kernel_launch(void* const* d_in, const int* in_sizes, int n_in,
                              void* d_out, int out_size, void* d_ws, size_t ws_size,
                              hipStream_t stream) {
    const float* x   = (const float*)d_in[0];
    const uint*  bpk = (const uint*)d_in[1];
    const float* s   = (const float*)d_in[2];
    float*       out = (float*)d_out;

    if (ws_size >= (size_t)(M_ * K_ * 2)) {
        xconv_kernel<<<128, 256, 0, stream>>>(x, (uint4*)d_ws);
        gemm_kernel<true><<<448, 512, 0, stream>>>(x, (const f16x8*)d_ws, bpk, s, out);
    } else {
        gemm_kernel<false><<<448, 512, 0, stream>>>(x, nullptr, bpk, s, out);
    }
}